// Round 1
// baseline (135.419 us; speedup 1.0000x reference)
//
#include <hip/hip_runtime.h>
#include <math.h>

// Problem constants
#define NN   768
#define HH   300
#define LDH  304          // padded leading dim for A/C matrices (multiple of 4)
#define KD   768
#define SZ   (NN*LDH)     // floats per staged matrix (233,472)

// ws float layout:
//  0*SZ: Cpart0   1*SZ: Cpart1   (hx partials, K-split halves)
//  2*SZ: Apart0   3*SZ: Apart1   (hy[perm]   partials)
//  4*SZ: Cfin     5*SZ: Afin     (Afin includes +b1)
//  6*SZ: esum[768]               (must be zeroed each launch)
//  6*SZ+1024: t0[768]

// ---------------- K1: fused GEMMs, fp32, 32x64 tile, BK=32, K split in 2 ----
__global__ __launch_bounds__(256) void k1_gemm(
    const float* __restrict__ x, const float* __restrict__ y,
    const int* __restrict__ perm, const float* __restrict__ W1,
    float* __restrict__ wsf)
{
    const int tid = threadIdx.x;
    const int tx = tid & 15, ty = tid >> 4;
    const int i0 = blockIdx.x * 32;
    const int h0 = blockIdx.y * 64;
    const int gemm = blockIdx.z & 1;   // 0: hx from x, 1: hy[perm] from y
    const int kh   = blockIdx.z >> 1;  // K half
    const int k_beg = kh * 384;

    const float* src = gemm ? y : x;
    const int koff = gemm ? KD : 0;

    __shared__ float xs[32][34];   // xs[k][i]
    __shared__ float ws[32][68];   // ws[k][h]

    float acc[2][4] = {{0,0,0,0},{0,0,0,0}};

    // staging maps
    const int srow = tid >> 3, sc4 = (tid & 7) << 2;      // x: 32 rows x 32 k
    int grow = i0 + srow;
    if (gemm) grow = perm[grow];
    const float* srcp = src + (size_t)grow * KD + sc4 + k_beg;

    const int hrow = tid >> 2, kc8 = (tid & 3) << 3;      // W1: 64 rows x 32 k
    const int hg = h0 + hrow;
    const bool hvalid = hg < HH;
    const float* wrow = W1 + (size_t)hg * (2*KD) + koff + kc8 + k_beg;

    for (int kc = 0; kc < 384; kc += 32) {
        float4 xv = *(const float4*)(srcp + kc);
        xs[sc4+0][srow] = xv.x; xs[sc4+1][srow] = xv.y;
        xs[sc4+2][srow] = xv.z; xs[sc4+3][srow] = xv.w;

        float4 w0 = make_float4(0,0,0,0), w1 = make_float4(0,0,0,0);
        if (hvalid) {
            w0 = *(const float4*)(wrow + kc);
            w1 = *(const float4*)(wrow + kc + 4);
        }
        ws[kc8+0][hrow]=w0.x; ws[kc8+1][hrow]=w0.y; ws[kc8+2][hrow]=w0.z; ws[kc8+3][hrow]=w0.w;
        ws[kc8+4][hrow]=w1.x; ws[kc8+5][hrow]=w1.y; ws[kc8+6][hrow]=w1.z; ws[kc8+7][hrow]=w1.w;
        __syncthreads();

        #pragma unroll
        for (int k = 0; k < 32; ++k) {
            float a0 = xs[k][2*ty], a1 = xs[k][2*ty+1];
            float b0 = ws[k][4*tx+0], b1v = ws[k][4*tx+1];
            float b2v = ws[k][4*tx+2], b3v = ws[k][4*tx+3];
            acc[0][0] = fmaf(a0,b0, acc[0][0]); acc[0][1] = fmaf(a0,b1v,acc[0][1]);
            acc[0][2] = fmaf(a0,b2v,acc[0][2]); acc[0][3] = fmaf(a0,b3v,acc[0][3]);
            acc[1][0] = fmaf(a1,b0, acc[1][0]); acc[1][1] = fmaf(a1,b1v,acc[1][1]);
            acc[1][2] = fmaf(a1,b2v,acc[1][2]); acc[1][3] = fmaf(a1,b3v,acc[1][3]);
        }
        __syncthreads();
    }

    float* dst = wsf + (gemm ? 2*(size_t)SZ : 0) + (size_t)kh * SZ;
    #pragma unroll
    for (int r = 0; r < 2; ++r) {
        int gi = i0 + 2*ty + r;
        #pragma unroll
        for (int c = 0; c < 4; ++c) {
            int hh = h0 + 4*tx + c;
            if (hh < HH) dst[(size_t)gi*LDH + hh] = acc[r][c];
        }
    }
}

// ---------------- K1b: combine K-partials; A gets +b1; pad cols -> 0 --------
__global__ __launch_bounds__(256) void k1b_combine(
    const float* __restrict__ b1, float* __restrict__ wsf)
{
    const int N4 = SZ/4;
    int idx = blockIdx.x * 256 + threadIdx.x;       // grid = 2*N4/256 = 456
    int which = idx >= N4 ? 1 : 0;                  // 0 = C, 1 = A
    int rem = idx - which * N4;
    int base = rem * 4;
    int h = base % LDH;
    const float* p0 = wsf + (which ? 2*(size_t)SZ : 0);
    const float* p1 = p0 + SZ;
    float* dst = wsf + (which ? 5*(size_t)SZ : 4*(size_t)SZ);

    float4 out = make_float4(0,0,0,0);
    if (h < HH) {   // h is mult of 4; h<300 => h<=296 => h+3<=299 all valid
        float4 v0 = *(const float4*)(p0 + base);
        float4 v1 = *(const float4*)(p1 + base);
        out.x = v0.x + v1.x; out.y = v0.y + v1.y;
        out.z = v0.z + v1.z; out.w = v0.w + v1.w;
        if (which) {
            float4 bv = *(const float4*)(b1 + h);
            out.x += bv.x; out.y += bv.y; out.z += bv.z; out.w += bv.w;
        }
    }
    *(float4*)(dst + base) = out;
}

// ---------------- K2: pairwise relu-dot + exp row-sums ----------------------
// tile: 32 i x 64 j, 256 threads (tx:16 -> 4 j, ty:16 -> 2 i), h chunks of 60
__global__ __launch_bounds__(256) void k2_pair(
    const float* __restrict__ wsf, const float* __restrict__ w2,
    const float* __restrict__ b2, float* __restrict__ esum)
{
    const int tid = threadIdx.x;
    const int tx = tid & 15, ty = tid >> 4;
    const int i0 = blockIdx.x * 32;
    const int j0 = blockIdx.y * 64;

    const float* Af = wsf + 5*(size_t)SZ;
    const float* Cf = wsf + 4*(size_t)SZ;

    __shared__ float As[60][34];   // As[h][i]
    __shared__ float Cs[60][68];   // Cs[h][j]
    __shared__ float ws2[60];

    float acc[2][4] = {{0,0,0,0},{0,0,0,0}};

    for (int hc = 0; hc < HH; hc += 60) {
        // stage A tile: 32 rows x 60 h = 480 float4-groups of 4h
        for (int e = tid; e < 480; e += 256) {
            int i = e / 15, h4 = (e % 15) * 4;
            float4 v = *(const float4*)(Af + (size_t)(i0 + i)*LDH + hc + h4);
            As[h4+0][i] = v.x; As[h4+1][i] = v.y; As[h4+2][i] = v.z; As[h4+3][i] = v.w;
        }
        // stage C tile: 64 rows x 60 h
        for (int e = tid; e < 960; e += 256) {
            int j = e / 15, h4 = (e % 15) * 4;
            float4 v = *(const float4*)(Cf + (size_t)(j0 + j)*LDH + hc + h4);
            Cs[h4+0][j] = v.x; Cs[h4+1][j] = v.y; Cs[h4+2][j] = v.z; Cs[h4+3][j] = v.w;
        }
        if (tid < 60) ws2[tid] = w2[hc + tid];
        __syncthreads();

        #pragma unroll 6
        for (int h = 0; h < 60; ++h) {
            float wh = ws2[h];
            float a0 = As[h][2*ty], a1 = As[h][2*ty+1];
            float4 cv = *(const float4*)&Cs[h][4*tx];
            float t;
            t = fmaxf(a0+cv.x,0.f); acc[0][0] = fmaf(t,wh,acc[0][0]);
            t = fmaxf(a0+cv.y,0.f); acc[0][1] = fmaf(t,wh,acc[0][1]);
            t = fmaxf(a0+cv.z,0.f); acc[0][2] = fmaf(t,wh,acc[0][2]);
            t = fmaxf(a0+cv.w,0.f); acc[0][3] = fmaf(t,wh,acc[0][3]);
            t = fmaxf(a1+cv.x,0.f); acc[1][0] = fmaf(t,wh,acc[1][0]);
            t = fmaxf(a1+cv.y,0.f); acc[1][1] = fmaf(t,wh,acc[1][1]);
            t = fmaxf(a1+cv.z,0.f); acc[1][2] = fmaf(t,wh,acc[1][2]);
            t = fmaxf(a1+cv.w,0.f); acc[1][3] = fmaf(t,wh,acc[1][3]);
        }
        __syncthreads();
    }

    // exp(s + b2), sum over this block's 64 j per i, one atomic per (i, block)
    const float b2v = b2[0];
    #pragma unroll
    for (int r = 0; r < 2; ++r) {
        float s = expf(acc[r][0] + b2v) + expf(acc[r][1] + b2v)
                + expf(acc[r][2] + b2v) + expf(acc[r][3] + b2v);
        // reduce across tx (lane bits 0..3 within the wave)
        s += __shfl_xor(s, 1);
        s += __shfl_xor(s, 2);
        s += __shfl_xor(s, 4);
        s += __shfl_xor(s, 8);
        if (tx == 0) atomicAdd(&esum[i0 + 2*ty + r], s);
    }
}

// ---------------- K2b: t0 (matched pairs), one wave per row -----------------
__global__ __launch_bounds__(256) void k2b_t0(
    const float* __restrict__ wsf, const int* __restrict__ perm,
    const float* __restrict__ w2, const float* __restrict__ b2,
    float* __restrict__ t0out)
{
    const int lane = threadIdx.x & 63;
    const int row  = blockIdx.x * 4 + (threadIdx.x >> 6);
    const float* Af = wsf + 5*(size_t)SZ;
    const float* Cf = wsf + 4*(size_t)SZ;
    const int pr = perm[row];

    float acc = 0.f;
    for (int h = lane; h < HH; h += 64) {
        float a = Af[(size_t)row*LDH + h];      // hy[perm[row]] + b1
        float c = Cf[(size_t)pr *LDH + h];      // hx[perm[row]]
        float z = fmaxf(a + c, 0.f);
        acc = fmaf(z, w2[h], acc);
    }
    #pragma unroll
    for (int m = 1; m < 64; m <<= 1) acc += __shfl_xor(acc, m);
    if (lane == 0) {
        float u = acc + b2[0];
        // softplus, numerically stable
        t0out[row] = (u > 0.f) ? u + log1pf(expf(-u)) : log1pf(expf(u));
    }
}

// ---------------- K3: final double-precision reduction ----------------------
__global__ __launch_bounds__(256) void k3_final(
    const float* __restrict__ wsf, float* __restrict__ out)
{
    const int tid = threadIdx.x;
    const float* esum = wsf + 6*(size_t)SZ;
    const float* t0   = wsf + 6*(size_t)SZ + 1024;

    double st0 = 0.0, slse = 0.0;
    for (int i = tid; i < NN; i += 256) {
        st0  += (double)t0[i];
        // logsumexp_j softplus = log(N + sum_j e^{s+b2})
        slse += log((double)NN + (double)esum[i]);
    }
    __shared__ double sa[256], sb[256];
    sa[tid] = st0; sb[tid] = slse;
    __syncthreads();
    for (int s = 128; s > 0; s >>= 1) {
        if (tid < s) { sa[tid] += sa[tid+s]; sb[tid] += sb[tid+s]; }
        __syncthreads();
    }
    if (tid == 0) {
        double lb = sa[0]/(double)NN - (sb[0]/(double)NN - log((double)NN));
        out[0] = (float)lb;
    }
}

extern "C" void kernel_launch(void* const* d_in, const int* in_sizes, int n_in,
                              void* d_out, int out_size, void* d_ws, size_t ws_size,
                              hipStream_t stream) {
    const float* x    = (const float*)d_in[0];
    const float* y    = (const float*)d_in[1];
    const int*   perm = (const int*)  d_in[2];
    const float* W1   = (const float*)d_in[3];
    const float* b1   = (const float*)d_in[4];
    const float* W2   = (const float*)d_in[5];
    const float* b2   = (const float*)d_in[6];
    float* wsf = (float*)d_ws;
    float* out = (float*)d_out;

    // zero esum (ws is poisoned 0xAA before every launch)
    hipMemsetAsync(wsf + 6*(size_t)SZ, 0, NN * sizeof(float), stream);

    k1_gemm   <<<dim3(24,5,4), 256, 0, stream>>>(x, y, perm, W1, wsf);
    k1b_combine<<<456,          256, 0, stream>>>(b1, wsf);
    k2_pair   <<<dim3(24,12),  256, 0, stream>>>(wsf, W2, b2, wsf + 6*(size_t)SZ);
    k2b_t0    <<<192,           256, 0, stream>>>(wsf, perm, W2, b2,
                                                  wsf + 6*(size_t)SZ + 1024);
    k3_final  <<<1,             256, 0, stream>>>(wsf, out);
}

// Round 2
// 126.503 us; speedup vs baseline: 1.0705x; 1.0705x over previous
//
#include <hip/hip_runtime.h>
#include <math.h>

// Problem constants
#define NN   768
#define HH   300
#define LDH  320          // H padded to 320 = 8 x 40 = 5 x 64
#define KD   768

// ---- ws float layout ----
// P:  [2 gemm][8 ksplit][768][320] partials         @ 0        (3,932,160 f)
// CF: hx final [768][320] (pads 0)                  @ 3932160
// AF: hy[perm]+b1 final [768][320] (pads 0)         @ 4177920
// SP: [8 hpart][768][768] pairwise dot partials     @ 4423680  (4,718,592 f)
// ES: esum[768]                                     @ 9142272
// T0: t0[768]                                       @ 9143040
#define P_OFF   0
#define P_STR   245760            // 768*320
#define CF_OFF  3932160
#define AF_OFF  4177920
#define SP_OFF  4423680
#define SP_STR  589824            // 768*768
#define ES_OFF  9142272
#define T0_OFF  9143040

// ================= K1: the two 768x300x768 GEMMs, fp32 =====================
// block tile 128i x 64h, per-thread 8i x 4h, K-split 8 (Kc=96), 256 threads.
// grid (6 i, 5 h, 16 = gemm*8+ks). Writes partial P[gemm][ks][i][h].
__global__ __launch_bounds__(256) void k1_gemm(
    const float* __restrict__ x, const float* __restrict__ y,
    const int* __restrict__ perm, const float* __restrict__ W1,
    float* __restrict__ wsf)
{
    const int tid = threadIdx.x;
    const int tx = tid & 15;          // h: cols 4tx..4tx+3
    const int ty = tid >> 4;          // i: rows {4ty..4ty+3} u {64+4ty..}
    const int i0 = blockIdx.x * 128;
    const int h0 = blockIdx.y * 64;
    const int gemm = blockIdx.z & 1;  // 0: hx from x, 1: hy[perm] from y
    const int ks   = blockIdx.z >> 1; // K slice
    const int kbeg = ks * 96;

    const float* src = gemm ? y : x;
    const int koff = gemm ? KD : 0;

    __shared__ float xs[32][132];     // xs[k][i], 128 i + pad
    __shared__ float ws[32][68];      // ws[k][h], 64 h + pad

    float4 acc[8];
    #pragma unroll
    for (int r = 0; r < 8; ++r) acc[r] = make_float4(0.f,0.f,0.f,0.f);

    for (int kc = 0; kc < 96; kc += 32) {
        const int kb = kbeg + kc;
        // stage x-tile: 128 rows x 32 k = 1024 float4, 4 per thread
        #pragma unroll
        for (int it = 0; it < 4; ++it) {
            int e = tid + it * 256;
            int row = e >> 3, kq = (e & 7) << 2;
            int grow = i0 + row;
            if (gemm) grow = perm[grow];
            float4 v = *(const float4*)(src + (size_t)grow * KD + kb + kq);
            xs[kq+0][row] = v.x; xs[kq+1][row] = v.y;
            xs[kq+2][row] = v.z; xs[kq+3][row] = v.w;
        }
        // stage W-tile: 64 rows x 32 k = 512 float4, 2 per thread
        #pragma unroll
        for (int it = 0; it < 2; ++it) {
            int e = tid + it * 256;
            int hrow = e >> 3, kq = (e & 7) << 2;
            int hg = h0 + hrow;
            float4 v = make_float4(0.f,0.f,0.f,0.f);
            if (hg < HH) v = *(const float4*)(W1 + (size_t)hg * (2*KD) + koff + kb + kq);
            ws[kq+0][hrow] = v.x; ws[kq+1][hrow] = v.y;
            ws[kq+2][hrow] = v.z; ws[kq+3][hrow] = v.w;
        }
        __syncthreads();

        #pragma unroll 8
        for (int k = 0; k < 32; ++k) {
            float4 a0 = *(const float4*)&xs[k][4*ty];
            float4 a1 = *(const float4*)&xs[k][64 + 4*ty];
            float4 b  = *(const float4*)&ws[k][4*tx];
            acc[0].x = fmaf(a0.x,b.x,acc[0].x); acc[0].y = fmaf(a0.x,b.y,acc[0].y);
            acc[0].z = fmaf(a0.x,b.z,acc[0].z); acc[0].w = fmaf(a0.x,b.w,acc[0].w);
            acc[1].x = fmaf(a0.y,b.x,acc[1].x); acc[1].y = fmaf(a0.y,b.y,acc[1].y);
            acc[1].z = fmaf(a0.y,b.z,acc[1].z); acc[1].w = fmaf(a0.y,b.w,acc[1].w);
            acc[2].x = fmaf(a0.z,b.x,acc[2].x); acc[2].y = fmaf(a0.z,b.y,acc[2].y);
            acc[2].z = fmaf(a0.z,b.z,acc[2].z); acc[2].w = fmaf(a0.z,b.w,acc[2].w);
            acc[3].x = fmaf(a0.w,b.x,acc[3].x); acc[3].y = fmaf(a0.w,b.y,acc[3].y);
            acc[3].z = fmaf(a0.w,b.z,acc[3].z); acc[3].w = fmaf(a0.w,b.w,acc[3].w);
            acc[4].x = fmaf(a1.x,b.x,acc[4].x); acc[4].y = fmaf(a1.x,b.y,acc[4].y);
            acc[4].z = fmaf(a1.x,b.z,acc[4].z); acc[4].w = fmaf(a1.x,b.w,acc[4].w);
            acc[5].x = fmaf(a1.y,b.x,acc[5].x); acc[5].y = fmaf(a1.y,b.y,acc[5].y);
            acc[5].z = fmaf(a1.y,b.z,acc[5].z); acc[5].w = fmaf(a1.y,b.w,acc[5].w);
            acc[6].x = fmaf(a1.z,b.x,acc[6].x); acc[6].y = fmaf(a1.z,b.y,acc[6].y);
            acc[6].z = fmaf(a1.z,b.z,acc[6].z); acc[6].w = fmaf(a1.z,b.w,acc[6].w);
            acc[7].x = fmaf(a1.w,b.x,acc[7].x); acc[7].y = fmaf(a1.w,b.y,acc[7].y);
            acc[7].z = fmaf(a1.w,b.z,acc[7].z); acc[7].w = fmaf(a1.w,b.w,acc[7].w);
        }
        __syncthreads();
    }

    float* dst = wsf + P_OFF + (size_t)(gemm*8 + ks) * P_STR;
    #pragma unroll
    for (int r = 0; r < 8; ++r) {
        int i = i0 + ((r < 4) ? (4*ty + r) : (64 + 4*ty + r - 4));
        *(float4*)(dst + (size_t)i * LDH + h0 + 4*tx) = acc[r];
    }
}

// ============ K1b: sum 8 K-partials; A += b1; pads -> 0 =====================
__global__ __launch_bounds__(256) void k1b_combine(
    const float* __restrict__ b1, float* __restrict__ wsf)
{
    const int HQ = LDH/4;                       // 80 float4 per row
    const int PER = NN * HQ;                    // 61440 per gemm
    int idx = blockIdx.x * 256 + threadIdx.x;   // grid 480 -> 122880 threads
    int gemm = idx >= PER ? 1 : 0;
    int rem = idx - gemm * PER;
    int i = rem / HQ;
    int h4 = (rem % HQ) * 4;

    float4 out = make_float4(0.f,0.f,0.f,0.f);
    if (h4 < HH) {
        const float* p = wsf + P_OFF + (size_t)gemm*8*P_STR + (size_t)i*LDH + h4;
        #pragma unroll
        for (int ks = 0; ks < 8; ++ks) {
            float4 v = *(const float4*)(p + (size_t)ks * P_STR);
            out.x += v.x; out.y += v.y; out.z += v.z; out.w += v.w;
        }
        if (gemm) {
            float4 bv = *(const float4*)(b1 + h4);
            out.x += bv.x; out.y += bv.y; out.z += bv.z; out.w += bv.w;
        }
    }
    float* dst = wsf + (gemm ? AF_OFF : CF_OFF);
    *(float4*)(dst + (size_t)i * LDH + h4) = out;
}

// ======== K2: pairwise relu-dot partials over h-chunks of 40 ================
// block 64i x 128j, per-thread 4i x 8j, grid (12,6,8). Writes SP[p][i][j].
__global__ __launch_bounds__(256) void k2_pair(
    const float* __restrict__ wsf, const float* __restrict__ w2,
    float* __restrict__ sp)
{
    const int tid = threadIdx.x;
    const int tx = tid & 15;          // j: {4tx..4tx+3} u {64+4tx..}
    const int ty = tid >> 4;          // i: 4ty..4ty+3
    const int i0 = blockIdx.x * 64;
    const int j0 = blockIdx.y * 128;
    const int p  = blockIdx.z;
    const int h0 = p * 40;

    const float* Af = wsf + AF_OFF;
    const float* Cf = wsf + CF_OFF;

    __shared__ float As[40][68];      // As[h][i]
    __shared__ float Cs[40][132];     // Cs[h][j]
    __shared__ float ws2[40];

    // stage A: 64 rows x 10 float4
    for (int e = tid; e < 640; e += 256) {
        int r = e / 10, q = (e % 10) * 4;
        float4 v = *(const float4*)(Af + (size_t)(i0 + r) * LDH + h0 + q);
        As[q+0][r] = v.x; As[q+1][r] = v.y; As[q+2][r] = v.z; As[q+3][r] = v.w;
    }
    // stage C: 128 rows x 10 float4
    for (int e = tid; e < 1280; e += 256) {
        int r = e / 10, q = (e % 10) * 4;
        float4 v = *(const float4*)(Cf + (size_t)(j0 + r) * LDH + h0 + q);
        Cs[q+0][r] = v.x; Cs[q+1][r] = v.y; Cs[q+2][r] = v.z; Cs[q+3][r] = v.w;
    }
    if (tid < 40) {
        int h = h0 + tid;
        ws2[tid] = (h < HH) ? w2[h] : 0.f;
    }
    __syncthreads();

    float4 a0 = make_float4(0,0,0,0);
    float acc[4][8];
    #pragma unroll
    for (int r = 0; r < 4; ++r)
        #pragma unroll
        for (int c = 0; c < 8; ++c) acc[r][c] = 0.f;

    #pragma unroll 4
    for (int h = 0; h < 40; ++h) {
        float wh = ws2[h];
        float4 av = *(const float4*)&As[h][4*ty];
        float4 c0 = *(const float4*)&Cs[h][4*tx];
        float4 c1 = *(const float4*)&Cs[h][64 + 4*tx];
        float ar[4] = {av.x, av.y, av.z, av.w};
        float cr[8] = {c0.x, c0.y, c0.z, c0.w, c1.x, c1.y, c1.z, c1.w};
        #pragma unroll
        for (int r = 0; r < 4; ++r) {
            #pragma unroll
            for (int c = 0; c < 8; ++c) {
                float t = fmaxf(ar[r] + cr[c], 0.f);
                acc[r][c] = fmaf(t, wh, acc[r][c]);
            }
        }
    }

    float* dst = sp + (size_t)p * SP_STR;
    #pragma unroll
    for (int r = 0; r < 4; ++r) {
        int i = i0 + 4*ty + r;
        *(float4*)(dst + (size_t)i * NN + j0 + 4*tx)      =
            make_float4(acc[r][0], acc[r][1], acc[r][2], acc[r][3]);
        *(float4*)(dst + (size_t)i * NN + j0 + 64 + 4*tx) =
            make_float4(acc[r][4], acc[r][5], acc[r][6], acc[r][7]);
    }
}

// ===== K2e: rows — combine h-partials + exp-rowsum (bid<768) or t0 ==========
__global__ __launch_bounds__(256) void k2e_rows(
    const float* __restrict__ wsf, const int* __restrict__ perm,
    const float* __restrict__ w2, const float* __restrict__ b2,
    float* __restrict__ esum, float* __restrict__ t0out)
{
    const int tid = threadIdx.x;
    __shared__ float red[256];
    const float b2v = b2[0];

    if ((int)blockIdx.x < NN) {
        const int row = blockIdx.x;
        const float* spr = wsf + SP_OFF + (size_t)row * NN;
        float e = 0.f;
        #pragma unroll
        for (int jj = 0; jj < 3; ++jj) {
            int j = tid + jj * 256;
            float s = 0.f;
            #pragma unroll
            for (int p = 0; p < 8; ++p) s += spr[(size_t)p * SP_STR + j];
            e += expf(s + b2v);
        }
        red[tid] = e;
        __syncthreads();
        for (int s = 128; s > 0; s >>= 1) {
            if (tid < s) red[tid] += red[tid + s];
            __syncthreads();
        }
        if (tid == 0) esum[row] = red[0];
    } else {
        const int row = blockIdx.x - NN;
        const int pr = perm[row];
        const float* Af = wsf + AF_OFF + (size_t)row * LDH;
        const float* Cf = wsf + CF_OFF + (size_t)pr  * LDH;
        float acc = 0.f;
        for (int h = tid; h < HH; h += 256) {
            float z = fmaxf(Af[h] + Cf[h], 0.f);
            acc = fmaf(z, w2[h], acc);
        }
        red[tid] = acc;
        __syncthreads();
        for (int s = 128; s > 0; s >>= 1) {
            if (tid < s) red[tid] += red[tid + s];
            __syncthreads();
        }
        if (tid == 0) {
            float u = red[0] + b2v;
            t0out[row] = (u > 0.f) ? u + log1pf(expf(-u)) : log1pf(expf(u));
        }
    }
}

// ================= K3: final double-precision reduction =====================
__global__ __launch_bounds__(256) void k3_final(
    const float* __restrict__ wsf, float* __restrict__ out)
{
    const int tid = threadIdx.x;
    const float* esum = wsf + ES_OFF;
    const float* t0   = wsf + T0_OFF;

    double st0 = 0.0, slse = 0.0;
    for (int i = tid; i < NN; i += 256) {
        st0  += (double)t0[i];
        slse += log((double)NN + (double)esum[i]);
    }
    __shared__ double sa[256], sb[256];
    sa[tid] = st0; sb[tid] = slse;
    __syncthreads();
    for (int s = 128; s > 0; s >>= 1) {
        if (tid < s) { sa[tid] += sa[tid+s]; sb[tid] += sb[tid+s]; }
        __syncthreads();
    }
    if (tid == 0) {
        double lb = sa[0]/(double)NN - (sb[0]/(double)NN - log((double)NN));
        out[0] = (float)lb;
    }
}

extern "C" void kernel_launch(void* const* d_in, const int* in_sizes, int n_in,
                              void* d_out, int out_size, void* d_ws, size_t ws_size,
                              hipStream_t stream) {
    const float* x    = (const float*)d_in[0];
    const float* y    = (const float*)d_in[1];
    const int*   perm = (const int*)  d_in[2];
    const float* W1   = (const float*)d_in[3];
    const float* b1   = (const float*)d_in[4];
    const float* W2   = (const float*)d_in[5];
    const float* b2   = (const float*)d_in[6];
    float* wsf = (float*)d_ws;
    float* out = (float*)d_out;

    k1_gemm    <<<dim3(6,5,16), 256, 0, stream>>>(x, y, perm, W1, wsf);
    k1b_combine<<<480,          256, 0, stream>>>(b1, wsf);
    k2_pair    <<<dim3(12,6,8), 256, 0, stream>>>(wsf, W2, wsf + SP_OFF);
    k2e_rows   <<<2*NN,         256, 0, stream>>>(wsf, perm, W2, b2,
                                                  wsf + ES_OFF, wsf + T0_OFF);
    k3_final   <<<1,            256, 0, stream>>>(wsf, out);
}